// Round 3
// baseline (1045.169 us; speedup 1.0000x reference)
//
#include <hip/hip_runtime.h>
#include <hip/hip_fp16.h>
#include <stdint.h>

// ---------------------------------------------------------------------------
// Problem geometry (all compile-time):
//   x: (64, 48, 512, 2, 2) fp32. seq[s,n,f] = x[n, f>>2, 8*s, (f>>1)&1, f&1]
//   (only batch rows n<64 of the 512 matter downstream).
//   Layer1 BiGRU: in=192, H=256, 64 steps. Layer2 BiGRU: in=512, H=256.
//   Only final hiddens of layer2 used. dec_h = w_adj @ [hf,hb] + b_adj.
//   Decoder GRU (in=56, H=256) 6 steps, out = w_fc1@h + b_fc1 -> (64,6,56).
//
// Scan kernels: 256 threads/block (4 waves -> 1 wave/SIMD -> 512 VGPR cap).
// Thread t owns Whh gate rows {t, 256+t, 512+t}: 96 uint4 = 384 f16x2 VGPRs,
// pinned via asm so the allocator cannot sink/remat the loads (round-2 lesson:
// at 768 threads the 170-VGPR cap forced reload-per-step => 232us decoder).
// ---------------------------------------------------------------------------

#define HD 256
#define G3 768
#define NSEQ 64
#define NSTEP 64

typedef _Float16 hvec2 __attribute__((ext_vector_type(2)));

__device__ __forceinline__ float sigmf(float x) {
    return 1.0f / (1.0f + __expf(-x));
}

#if __has_builtin(__builtin_amdgcn_fdot2)
__device__ __forceinline__ float fdot2u(uint32_t w, uint32_t h, float acc) {
    return __builtin_amdgcn_fdot2(__builtin_bit_cast(hvec2, w),
                                  __builtin_bit_cast(hvec2, h), acc, false);
}
#else
__device__ __forceinline__ float fdot2u(uint32_t w, uint32_t h, float acc) {
    const __half2 wv = __builtin_bit_cast(__half2, w);
    const __half2 hv = __builtin_bit_cast(__half2, h);
    acc += __half2float(wv.x) * __half2float(hv.x);
    acc += __half2float(wv.y) * __half2float(hv.y);
    return acc;
}
#endif

__device__ __forceinline__ uint32_t pkh(float a, float b) {
    uint32_t lo = __half_as_ushort(__float2half_rn(a));
    uint32_t hi = __half_as_ushort(__float2half_rn(b));
    return lo | (hi << 16);
}

#define L32(X) X(0) X(1) X(2) X(3) X(4) X(5) X(6) X(7) \
  X(8) X(9) X(10) X(11) X(12) X(13) X(14) X(15) \
  X(16) X(17) X(18) X(19) X(20) X(21) X(22) X(23) \
  X(24) X(25) X(26) X(27) X(28) X(29) X(30) X(31)

#define PIN(v) asm volatile("" : "+v"(v.x), "+v"(v.y), "+v"(v.z), "+v"(v.w));

// load all 3 gate rows for this thread (j = t, 256+t, 512+t)
#define LOADW(i) \
    uint4 wr##i = wq[(i) * G3 + t];        PIN(wr##i) \
    uint4 wz##i = wq[(i) * G3 + 256 + t];  PIN(wz##i) \
    uint4 wn##i = wq[(i) * G3 + 512 + t];  PIN(wn##i)

// one K-chunk (8 h values) applied to all 3 gate rows
#define DOTW(q) { const uint4 hp = *(const uint4*)&hb[4 * (q)]; \
    ar0 = fdot2u(wr##q.x, hp.x, ar0); ar1 = fdot2u(wr##q.y, hp.y, ar1); \
    ar2 = fdot2u(wr##q.z, hp.z, ar2); ar3 = fdot2u(wr##q.w, hp.w, ar3); \
    az0 = fdot2u(wz##q.x, hp.x, az0); az1 = fdot2u(wz##q.y, hp.y, az1); \
    az2 = fdot2u(wz##q.z, hp.z, az2); az3 = fdot2u(wz##q.w, hp.w, az3); \
    an0 = fdot2u(wn##q.x, hp.x, an0); an1 = fdot2u(wn##q.y, hp.y, an1); \
    an2 = fdot2u(wn##q.z, hp.z, an2); an3 = fdot2u(wn##q.w, hp.w, an3); }

// ---------------- weight prep ----------------
// Repack Whh (768x256 fp32) -> uint4[q*768 + j], q=0..31: k=8q..8q+7 of row j.
__global__ __launch_bounds__(256) void pack_whhT(
    const float* __restrict__ w0, const float* __restrict__ w1,
    const float* __restrict__ w2, const float* __restrict__ w3,
    const float* __restrict__ w4,
    uint32_t* __restrict__ o0, uint32_t* __restrict__ o1,
    uint32_t* __restrict__ o2, uint32_t* __restrict__ o3,
    uint32_t* __restrict__ o4)
{
    const float* w; uint32_t* o;
    switch (blockIdx.y) {
        case 0: w = w0; o = o0; break;
        case 1: w = w1; o = o1; break;
        case 2: w = w2; o = o2; break;
        case 3: w = w3; o = o3; break;
        default: w = w4; o = o4; break;
    }
    int idx = blockIdx.x * 256 + threadIdx.x;    // 24576 total
    int j = idx >> 5, q = idx & 31;
    const float4 fa = *(const float4*)(w + j * HD + 8 * q);
    const float4 fb = *(const float4*)(w + j * HD + 8 * q + 4);
    uint4 r;
    r.x = pkh(fa.x, fa.y);
    r.y = pkh(fa.z, fa.w);
    r.z = pkh(fb.x, fb.y);
    r.w = pkh(fb.z, fb.w);
    ((uint4*)o)[q * G3 + j] = r;
}

// fp32 transposes for decoder-input / adj / fc1 paths
__global__ __launch_bounds__(256) void prep_small(
    const float* __restrict__ wihd,   // (768,56)
    const float* __restrict__ wadj,   // (256,512)
    const float* __restrict__ wfc1,   // (56,256)
    float* __restrict__ wihdT,        // [v][j] 56x768
    float* __restrict__ wadjT,        // [f][i] 512x256
    float* __restrict__ wfc1T)        // [k][v] 256x56
{
    int idx = blockIdx.x * 256 + threadIdx.x;    // 188416 total
    if (idx < 43008) {
        int v = idx / G3, j = idx % G3;
        wihdT[idx] = wihd[j * 56 + v];
    } else if (idx < 43008 + 131072) {
        int i2 = idx - 43008;
        int f = i2 / HD, i = i2 % HD;
        wadjT[i2] = wadj[i * 512 + f];
    } else {
        int i3 = idx - 174080;
        int k = i3 / 56, v = i3 % 56;
        wfc1T[i3] = wfc1[v * HD + k];
    }
}

// gather seq rows: seqg[(n*64+s)*192 + f] = x[n, f>>2, 8s, (f>>1)&1, f&1]
__global__ __launch_bounds__(256) void gather_seq(
    const float* __restrict__ x, float* __restrict__ seqg)
{
    int idx = blockIdx.x * 256 + threadIdx.x;    // 786432 total
    int f = idx % 192;
    int m = idx / 192;
    int n = m >> 6, s = m & 63;
    seqg[idx] = x[n * 98304 + (f >> 2) * 2048 + s * 32 + (f & 3)];
}

// ---------------- fp32 tiled GEMM with bias ----------------
__global__ __launch_bounds__(256) void gemm_bias(
    const float* __restrict__ A,
    const float* __restrict__ B0, const float* __restrict__ B1,
    const float* __restrict__ bias0, const float* __restrict__ bias1,
    float* __restrict__ C0, float* __restrict__ C1, int K)
{
    const float* B    = blockIdx.z ? B1 : B0;
    const float* bias = blockIdx.z ? bias1 : bias0;
    float*       C    = blockIdx.z ? C1 : C0;
    const int m0 = blockIdx.x * 64;
    const int n0 = blockIdx.y * 64;
    const int tid = threadIdx.x;
    const int tx = tid & 15, ty = tid >> 4;

    __shared__ float As[16][64];
    __shared__ float Bs[16][64];

    const int lm = tid >> 2;
    const int lk = (tid & 3) * 4;
    const int sw = lk << 2;

    float acc[4][4] = {};
    for (int k0 = 0; k0 < K; k0 += 16) {
        float4 a = *(const float4*)(A + (size_t)(m0 + lm) * K + k0 + lk);
        float4 b = *(const float4*)(B + (size_t)(n0 + lm) * K + k0 + lk);
        __syncthreads();
        As[lk + 0][lm ^ sw] = a.x; As[lk + 1][lm ^ sw] = a.y;
        As[lk + 2][lm ^ sw] = a.z; As[lk + 3][lm ^ sw] = a.w;
        Bs[lk + 0][lm ^ sw] = b.x; Bs[lk + 1][lm ^ sw] = b.y;
        Bs[lk + 2][lm ^ sw] = b.z; Bs[lk + 3][lm ^ sw] = b.w;
        __syncthreads();
#pragma unroll
        for (int kk = 0; kk < 16; ++kk) {
            const int swk = ((kk >> 2) & 3) << 4;
            const float4 a4 = *(const float4*)&As[kk][(ty * 4) ^ swk];
            const float4 b4 = *(const float4*)&Bs[kk][(tx * 4) ^ swk];
            const float av[4] = {a4.x, a4.y, a4.z, a4.w};
            const float bv[4] = {b4.x, b4.y, b4.z, b4.w};
#pragma unroll
            for (int i = 0; i < 4; ++i)
#pragma unroll
                for (int j = 0; j < 4; ++j)
                    acc[i][j] += av[i] * bv[j];
        }
    }
#pragma unroll
    for (int i = 0; i < 4; ++i) {
#pragma unroll
        for (int j = 0; j < 4; ++j) {
            C[(size_t)(m0 + ty * 4 + i) * G3 + n0 + tx * 4 + j] =
                acc[i][j] + bias[n0 + tx * 4 + j];
        }
    }
}

// ---------------- register-resident GRU scan ----------------
// 256 threads; thread t owns gate rows {t,256+t,512+t} (384 weight VGPRs).
// h double-buffered in LDS as f16x2 -> ONE barrier per step.
// grid = 128 blocks: dir = blockIdx.x&1, n = blockIdx.x>>1.
__global__ __launch_bounds__(256, 1) void gru_scan(
    const float* __restrict__ giF, const float* __restrict__ giB,
    const uint32_t* __restrict__ wTF, const uint32_t* __restrict__ wTB,
    const float* __restrict__ bhhF, const float* __restrict__ bhhB,
    float* __restrict__ y1, float* __restrict__ hfin, int mode)
{
    const int dir = blockIdx.x & 1;
    const int n   = blockIdx.x >> 1;
    const int t   = threadIdx.x;
    const float* gi  = dir ? giB : giF;
    const uint4* wq  = (const uint4*)(dir ? wTB : wTF);
    const float* bhh = dir ? bhhB : bhhF;

    __shared__ __align__(16) uint32_t h1u[2][HD / 2];

    L32(LOADW)
    const float bhr = bhh[t], bhz = bhh[256 + t], bhn = bhh[512 + t];

    float h_own = 0.0f;
    if (t < HD / 2) h1u[0][t] = 0u;
    __syncthreads();

    const float* gbase = gi + (size_t)n * NSTEP * G3;
    int s = dir ? (NSTEP - 1) : 0;
    float g_r = gbase[s * G3 + t];
    float g_z = gbase[s * G3 + 256 + t];
    float g_n = gbase[s * G3 + 512 + t];

    for (int step = 0; step < NSTEP; ++step) {
        const int s_nxt = dir ? (step < NSTEP - 1 ? NSTEP - 2 - step : 0)
                              : (step < NSTEP - 1 ? step + 1 : NSTEP - 1);
        const float gn_r = gbase[s_nxt * G3 + t];
        const float gn_z = gbase[s_nxt * G3 + 256 + t];
        const float gn_n = gbase[s_nxt * G3 + 512 + t];

        const uint32_t* hb = h1u[step & 1];
        float ar0 = 0.f, ar1 = 0.f, ar2 = 0.f, ar3 = 0.f;
        float az0 = 0.f, az1 = 0.f, az2 = 0.f, az3 = 0.f;
        float an0 = 0.f, an1 = 0.f, an2 = 0.f, an3 = 0.f;
        L32(DOTW)

        const float ghr = bhr + ((ar0 + ar1) + (ar2 + ar3));
        const float ghz = bhz + ((az0 + az1) + (az2 + az3));
        const float ghn = bhn + ((an0 + an1) + (an2 + an3));
        const float r  = sigmf(g_r + ghr);
        const float z  = sigmf(g_z + ghz);
        const float nn = tanhf(g_n + r * ghn);
        const float hnew = (1.0f - z) * nn + z * h_own;
        h_own = hnew;
        ((__half*)h1u[(step + 1) & 1])[t] = __float2half(hnew);
        if (mode == 0)
            y1[(size_t)(n * NSTEP + s) * 512 + dir * HD + t] = hnew;
        s = s_nxt;
        g_r = gn_r; g_z = gn_z; g_n = gn_n;
        __syncthreads();
    }
    if (mode == 1)
        hfin[(size_t)(dir * NSEQ + n) * HD + t] = h_own;
}

// ---------------- dec_h = w_adj @ [hf,hb] + b_adj ----------------
__global__ __launch_bounds__(256) void adj_kernel(
    const float* __restrict__ hfin, const float* __restrict__ wadjT,
    const float* __restrict__ badj, float* __restrict__ dech)
{
    const int n = blockIdx.x, t = threadIdx.x;
    __shared__ float comb[512];
    comb[t]      = hfin[(size_t)n * HD + t];
    comb[HD + t] = hfin[(size_t)(NSEQ + n) * HD + t];
    __syncthreads();
    float acc = badj[t];
#pragma unroll 8
    for (int f = 0; f < 512; ++f) acc += wadjT[f * HD + t] * comb[f];
    dech[n * HD + t] = acc;
}

// ---------------- decoder: 6 GRU steps + fc1, feeds output back ----------------
__global__ __launch_bounds__(256, 1) void decoder_kernel(
    const float* __restrict__ dech, const uint32_t* __restrict__ wTd,
    const float* __restrict__ wihdT, const float* __restrict__ bihd,
    const float* __restrict__ bhhd, const float* __restrict__ wfc1T,
    const float* __restrict__ bfc1, float* __restrict__ out)
{
    const int n = blockIdx.x, t = threadIdx.x;
    const uint4* wq = (const uint4*)wTd;

    __shared__ __align__(16) uint32_t h1u[2][HD / 2];
    __shared__ float hfp[HD];
    __shared__ float inp[56];

    L32(LOADW)
    const float bir = bihd[t], biz = bihd[256 + t], bin = bihd[512 + t];
    const float bhr = bhhd[t], bhz = bhhd[256 + t], bhn = bhhd[512 + t];

    const float hv = dech[n * HD + t];
    float h_own = hv;
    ((__half*)h1u[0])[t] = __float2half(hv);
    hfp[t] = hv;
    if (t < 56) inp[t] = 0.0f;
    __syncthreads();

    for (int step = 0; step < 6; ++step) {
        // input-gate matvec (56-dot per gate row), inp broadcast from LDS
        float ai_r = bir, ai_z = biz, ai_n = bin;
#pragma unroll
        for (int v = 0; v < 56; ++v) {
            const float iv = inp[v];
            ai_r += wihdT[v * G3 + t] * iv;
            ai_z += wihdT[v * G3 + 256 + t] * iv;
            ai_n += wihdT[v * G3 + 512 + t] * iv;
        }
        const uint32_t* hb = h1u[step & 1];
        float ar0 = 0.f, ar1 = 0.f, ar2 = 0.f, ar3 = 0.f;
        float az0 = 0.f, az1 = 0.f, az2 = 0.f, az3 = 0.f;
        float an0 = 0.f, an1 = 0.f, an2 = 0.f, an3 = 0.f;
        L32(DOTW)

        const float ghr = bhr + ((ar0 + ar1) + (ar2 + ar3));
        const float ghz = bhz + ((az0 + az1) + (az2 + az3));
        const float ghn = bhn + ((an0 + an1) + (an2 + an3));
        const float r  = sigmf(ai_r + ghr);
        const float z  = sigmf(ai_z + ghz);
        const float nn = tanhf(ai_n + r * ghn);
        const float hnew = (1.0f - z) * nn + z * h_own;
        h_own = hnew;
        ((__half*)h1u[(step + 1) & 1])[t] = __float2half(hnew);
        hfp[t] = hnew;
        __syncthreads();

        if (t < 56) {
            float o = bfc1[t];
#pragma unroll 8
            for (int k = 0; k < HD; ++k) o += wfc1T[k * 56 + t] * hfp[k];
            out[n * 336 + step * 56 + t] = o;
            inp[t] = o;
        }
        __syncthreads();
    }
}

// ---------------------------------------------------------------------------
extern "C" void kernel_launch(void* const* d_in, const int* in_sizes, int n_in,
                              void* d_out, int out_size, void* d_ws, size_t ws_size,
                              hipStream_t stream)
{
    const float* x      = (const float*)d_in[0];
    const float* wih1f  = (const float*)d_in[1];
    const float* whh1f  = (const float*)d_in[2];
    const float* bih1f  = (const float*)d_in[3];
    const float* bhh1f  = (const float*)d_in[4];
    const float* wih1b  = (const float*)d_in[5];
    const float* whh1b  = (const float*)d_in[6];
    const float* bih1b  = (const float*)d_in[7];
    const float* bhh1b  = (const float*)d_in[8];
    const float* wih2f  = (const float*)d_in[9];
    const float* whh2f  = (const float*)d_in[10];
    const float* bih2f  = (const float*)d_in[11];
    const float* bhh2f  = (const float*)d_in[12];
    const float* wih2b  = (const float*)d_in[13];
    const float* whh2b  = (const float*)d_in[14];
    const float* bih2b  = (const float*)d_in[15];
    const float* bhh2b  = (const float*)d_in[16];
    const float* wihd   = (const float*)d_in[17];
    const float* whhd   = (const float*)d_in[18];
    const float* bihd   = (const float*)d_in[19];
    const float* bhhd   = (const float*)d_in[20];
    const float* wfc1   = (const float*)d_in[21];
    const float* bfc1   = (const float*)d_in[22];
    const float* wadj   = (const float*)d_in[23];
    const float* badj   = (const float*)d_in[24];

    float* ws = (float*)d_ws;
    float* seqg  = ws + 0;              // 786432
    float* gi1f  = ws + 786432;         // 3145728  (also gi2f, after scan1)
    float* gi1b  = ws + 3932160;        // 3145728  (also gi2b)
    float* y1    = ws + 7077888;        // 2097152
    float* hfin  = ws + 9175040;        // 32768
    float* dech  = ws + 9207808;        // 16384
    uint32_t* wt1f  = (uint32_t*)(ws + 9224192);   // 98304 each
    uint32_t* wt1b  = (uint32_t*)(ws + 9322496);
    uint32_t* wt2f  = (uint32_t*)(ws + 9420800);
    uint32_t* wt2b  = (uint32_t*)(ws + 9519104);
    uint32_t* wtd   = (uint32_t*)(ws + 9617408);
    float* wihdT = ws + 9715712;        // 43008
    float* wadjT = ws + 9758720;        // 131072
    float* wfc1T = ws + 9889792;        // 14336

    pack_whhT<<<dim3(96, 5), 256, 0, stream>>>(
        whh1f, whh1b, whh2f, whh2b, whhd, wt1f, wt1b, wt2f, wt2b, wtd);
    prep_small<<<736, 256, 0, stream>>>(wihd, wadj, wfc1, wihdT, wadjT, wfc1T);
    gather_seq<<<3072, 256, 0, stream>>>(x, seqg);

    // layer 1
    gemm_bias<<<dim3(64, 12, 2), 256, 0, stream>>>(
        seqg, wih1f, wih1b, bih1f, bih1b, gi1f, gi1b, 192);
    gru_scan<<<128, 256, 0, stream>>>(
        gi1f, gi1b, wt1f, wt1b, bhh1f, bhh1b, y1, hfin, 0);

    // layer 2 (gi buffers reused; stream order serializes)
    gemm_bias<<<dim3(64, 12, 2), 256, 0, stream>>>(
        y1, wih2f, wih2b, bih2f, bih2b, gi1f, gi1b, 512);
    gru_scan<<<128, 256, 0, stream>>>(
        gi1f, gi1b, wt2f, wt2b, bhh2f, bhh2b, y1, hfin, 1);

    // decoder head
    adj_kernel<<<64, 256, 0, stream>>>(hfin, wadjT, badj, dech);
    decoder_kernel<<<64, 256, 0, stream>>>(
        dech, wtd, wihdT, bihd, bhhd, wfc1T, bfc1, (float*)d_out);
}

// Round 4
// 588.817 us; speedup vs baseline: 1.7750x; 1.7750x over previous
//
#include <hip/hip_runtime.h>
#include <hip/hip_fp16.h>
#include <stdint.h>

// ---------------------------------------------------------------------------
// Problem geometry (all compile-time):
//   x: (64, 48, 512, 2, 2) fp32. seq[s,n,f] = x[n, f>>2, 8*s, (f>>1)&1, f&1]
//   (only batch rows n<64 of the 512 matter downstream).
//   Layer1 BiGRU: in=192, H=256, 64 steps. Layer2 BiGRU: in=512, H=256.
//   Only final hiddens of layer2 used. dec_h = w_adj @ [hf,hb] + b_adj.
//   Decoder GRU (in=56, H=256) 6 steps, out = w_fc1@h + b_fc1 -> (64,6,56).
//
// Scan kernels: 512 threads/block, 8 waves = 2 waves/SIMD, cap 256 VGPR
// (CDNA arch limit: VALU addresses only 256 VGPRs/lane — round-3 lesson:
// 384 pinned weight regs => forced spill, 28MB scratch writes, 377us decoder).
// Thread (kh=t>>8, tr=t&255) owns gate rows {tr,256+tr,512+tr} for k-half kh:
// 48 uint4 = 192 weight VGPRs, pinned. Partial dots combined through LDS.
// ---------------------------------------------------------------------------

#define HD 256
#define G3 768
#define NSEQ 64
#define NSTEP 64

typedef _Float16 hvec2 __attribute__((ext_vector_type(2)));

__device__ __forceinline__ float sigmf(float x) {
    return 1.0f / (1.0f + __expf(-x));
}

#if __has_builtin(__builtin_amdgcn_fdot2)
__device__ __forceinline__ float fdot2u(uint32_t w, uint32_t h, float acc) {
    return __builtin_amdgcn_fdot2(__builtin_bit_cast(hvec2, w),
                                  __builtin_bit_cast(hvec2, h), acc, false);
}
#else
__device__ __forceinline__ float fdot2u(uint32_t w, uint32_t h, float acc) {
    const __half2 wv = __builtin_bit_cast(__half2, w);
    const __half2 hv = __builtin_bit_cast(__half2, h);
    acc += __half2float(wv.x) * __half2float(hv.x);
    acc += __half2float(wv.y) * __half2float(hv.y);
    return acc;
}
#endif

__device__ __forceinline__ uint32_t pkh(float a, float b) {
    uint32_t lo = __half_as_ushort(__float2half_rn(a));
    uint32_t hi = __half_as_ushort(__float2half_rn(b));
    return lo | (hi << 16);
}

#define L16(X) X(0) X(1) X(2) X(3) X(4) X(5) X(6) X(7) \
  X(8) X(9) X(10) X(11) X(12) X(13) X(14) X(15)

#define PIN(v) asm volatile("" : "+v"(v.x), "+v"(v.y), "+v"(v.z), "+v"(v.w));

// load this thread's 3 gate rows, k-chunk qb+i (qb = kh*16)
#define LOADW(i) \
    uint4 wr##i = wq[(qb + (i)) * G3 + tr];        PIN(wr##i) \
    uint4 wz##i = wq[(qb + (i)) * G3 + 256 + tr];  PIN(wz##i) \
    uint4 wn##i = wq[(qb + (i)) * G3 + 512 + tr];  PIN(wn##i)

// one K-chunk (8 h values) into 2 accumulators per gate
#define DOTW(i) { const uint4 hp = *(const uint4*)&hb[hoff + 4 * (i)]; \
    ar0 = fdot2u(wr##i.x, hp.x, ar0); ar1 = fdot2u(wr##i.y, hp.y, ar1); \
    ar0 = fdot2u(wr##i.z, hp.z, ar0); ar1 = fdot2u(wr##i.w, hp.w, ar1); \
    az0 = fdot2u(wz##i.x, hp.x, az0); az1 = fdot2u(wz##i.y, hp.y, az1); \
    az0 = fdot2u(wz##i.z, hp.z, az0); az1 = fdot2u(wz##i.w, hp.w, az1); \
    an0 = fdot2u(wn##i.x, hp.x, an0); an1 = fdot2u(wn##i.y, hp.y, an1); \
    an0 = fdot2u(wn##i.z, hp.z, an0); an1 = fdot2u(wn##i.w, hp.w, an1); }

// ---------------- weight prep ----------------
// Repack Whh (768x256 fp32) -> uint4[q*768 + j], q=0..31: k=8q..8q+7 of row j.
__global__ __launch_bounds__(256) void pack_whhT(
    const float* __restrict__ w0, const float* __restrict__ w1,
    const float* __restrict__ w2, const float* __restrict__ w3,
    const float* __restrict__ w4,
    uint32_t* __restrict__ o0, uint32_t* __restrict__ o1,
    uint32_t* __restrict__ o2, uint32_t* __restrict__ o3,
    uint32_t* __restrict__ o4)
{
    const float* w; uint32_t* o;
    switch (blockIdx.y) {
        case 0: w = w0; o = o0; break;
        case 1: w = w1; o = o1; break;
        case 2: w = w2; o = o2; break;
        case 3: w = w3; o = o3; break;
        default: w = w4; o = o4; break;
    }
    int idx = blockIdx.x * 256 + threadIdx.x;    // 24576 total
    int j = idx >> 5, q = idx & 31;
    const float4 fa = *(const float4*)(w + j * HD + 8 * q);
    const float4 fb = *(const float4*)(w + j * HD + 8 * q + 4);
    uint4 r;
    r.x = pkh(fa.x, fa.y);
    r.y = pkh(fa.z, fa.w);
    r.z = pkh(fb.x, fb.y);
    r.w = pkh(fb.z, fb.w);
    ((uint4*)o)[q * G3 + j] = r;
}

// fp32 transposes for decoder-input / adj / fc1 paths
__global__ __launch_bounds__(256) void prep_small(
    const float* __restrict__ wihd,   // (768,56)
    const float* __restrict__ wadj,   // (256,512)
    const float* __restrict__ wfc1,   // (56,256)
    float* __restrict__ wihdT,        // [v][j] 56x768
    float* __restrict__ wadjT,        // [f][i] 512x256
    float* __restrict__ wfc1T)        // [k][v] 256x56
{
    int idx = blockIdx.x * 256 + threadIdx.x;    // 188416 total
    if (idx < 43008) {
        int v = idx / G3, j = idx % G3;
        wihdT[idx] = wihd[j * 56 + v];
    } else if (idx < 43008 + 131072) {
        int i2 = idx - 43008;
        int f = i2 / HD, i = i2 % HD;
        wadjT[i2] = wadj[i * 512 + f];
    } else {
        int i3 = idx - 174080;
        int k = i3 / 56, v = i3 % 56;
        wfc1T[i3] = wfc1[v * HD + k];
    }
}

// gather seq rows: seqg[(n*64+s)*192 + f] = x[n, f>>2, 8s, (f>>1)&1, f&1]
__global__ __launch_bounds__(256) void gather_seq(
    const float* __restrict__ x, float* __restrict__ seqg)
{
    int idx = blockIdx.x * 256 + threadIdx.x;    // 786432 total
    int f = idx % 192;
    int m = idx / 192;
    int n = m >> 6, s = m & 63;
    seqg[idx] = x[n * 98304 + (f >> 2) * 2048 + s * 32 + (f & 3)];
}

// ---------------- fp32 tiled GEMM with bias ----------------
__global__ __launch_bounds__(256) void gemm_bias(
    const float* __restrict__ A,
    const float* __restrict__ B0, const float* __restrict__ B1,
    const float* __restrict__ bias0, const float* __restrict__ bias1,
    float* __restrict__ C0, float* __restrict__ C1, int K)
{
    const float* B    = blockIdx.z ? B1 : B0;
    const float* bias = blockIdx.z ? bias1 : bias0;
    float*       C    = blockIdx.z ? C1 : C0;
    const int m0 = blockIdx.x * 64;
    const int n0 = blockIdx.y * 64;
    const int tid = threadIdx.x;
    const int tx = tid & 15, ty = tid >> 4;

    __shared__ float As[16][64];
    __shared__ float Bs[16][64];

    const int lm = tid >> 2;
    const int lk = (tid & 3) * 4;
    const int sw = lk << 2;

    float acc[4][4] = {};
    for (int k0 = 0; k0 < K; k0 += 16) {
        float4 a = *(const float4*)(A + (size_t)(m0 + lm) * K + k0 + lk);
        float4 b = *(const float4*)(B + (size_t)(n0 + lm) * K + k0 + lk);
        __syncthreads();
        As[lk + 0][lm ^ sw] = a.x; As[lk + 1][lm ^ sw] = a.y;
        As[lk + 2][lm ^ sw] = a.z; As[lk + 3][lm ^ sw] = a.w;
        Bs[lk + 0][lm ^ sw] = b.x; Bs[lk + 1][lm ^ sw] = b.y;
        Bs[lk + 2][lm ^ sw] = b.z; Bs[lk + 3][lm ^ sw] = b.w;
        __syncthreads();
#pragma unroll
        for (int kk = 0; kk < 16; ++kk) {
            const int swk = ((kk >> 2) & 3) << 4;
            const float4 a4 = *(const float4*)&As[kk][(ty * 4) ^ swk];
            const float4 b4 = *(const float4*)&Bs[kk][(tx * 4) ^ swk];
            const float av[4] = {a4.x, a4.y, a4.z, a4.w};
            const float bv[4] = {b4.x, b4.y, b4.z, b4.w};
#pragma unroll
            for (int i = 0; i < 4; ++i)
#pragma unroll
                for (int j = 0; j < 4; ++j)
                    acc[i][j] += av[i] * bv[j];
        }
    }
#pragma unroll
    for (int i = 0; i < 4; ++i) {
#pragma unroll
        for (int j = 0; j < 4; ++j) {
            C[(size_t)(m0 + ty * 4 + i) * G3 + n0 + tx * 4 + j] =
                acc[i][j] + bias[n0 + tx * 4 + j];
        }
    }
}

// ---------------- register-resident GRU scan (split-K, 512 threads) --------
// grid = 128 blocks: dir = blockIdx.x&1, n = blockIdx.x>>1.
__global__ __launch_bounds__(512, 2) void gru_scan(
    const float* __restrict__ giF, const float* __restrict__ giB,
    const uint32_t* __restrict__ wTF, const uint32_t* __restrict__ wTB,
    const float* __restrict__ bhhF, const float* __restrict__ bhhB,
    float* __restrict__ y1, float* __restrict__ hfin, int mode)
{
    const int dir = blockIdx.x & 1;
    const int n   = blockIdx.x >> 1;
    const int t   = threadIdx.x;
    const int tr  = t & 255;
    const int kh  = t >> 8;          // k-half: 0 -> k<128, 1 -> k>=128
    const int qb  = kh * 16;
    const int hoff = kh * 64;        // offset into h buffer (u32 units)
    const float* gi  = dir ? giB : giF;
    const uint4* wq  = (const uint4*)(dir ? wTB : wTF);
    const float* bhh = dir ? bhhB : bhhF;

    __shared__ __align__(16) uint32_t h1u[2][HD / 2];  // h as f16x2, dbuf
    __shared__ float ph_r[HD], ph_z[HD], ph_n[HD];     // upper-half partials

    L16(LOADW)
    const float bhr = bhh[tr], bhz = bhh[256 + tr], bhn = bhh[512 + tr];

    float h_own = 0.0f;
    if (t < HD / 2) { h1u[0][t] = 0u; }
    __syncthreads();

    const float* gbase = gi + (size_t)n * NSTEP * G3;
    int s = dir ? (NSTEP - 1) : 0;
    float g_r = 0.f, g_z = 0.f, g_n = 0.f;
    if (kh == 0) {
        g_r = gbase[s * G3 + tr];
        g_z = gbase[s * G3 + 256 + tr];
        g_n = gbase[s * G3 + 512 + tr];
    }

    for (int step = 0; step < NSTEP; ++step) {
        const int s_nxt = dir ? (step < NSTEP - 1 ? NSTEP - 2 - step : 0)
                              : (step < NSTEP - 1 ? step + 1 : NSTEP - 1);
        float gn_r = 0.f, gn_z = 0.f, gn_n = 0.f;
        if (kh == 0) {
            gn_r = gbase[s_nxt * G3 + tr];
            gn_z = gbase[s_nxt * G3 + 256 + tr];
            gn_n = gbase[s_nxt * G3 + 512 + tr];
        }

        const uint32_t* hb = h1u[step & 1];
        float ar0 = 0.f, ar1 = 0.f;
        float az0 = 0.f, az1 = 0.f;
        float an0 = 0.f, an1 = 0.f;
        L16(DOTW)

        if (kh) {
            ph_r[tr] = ar0 + ar1;
            ph_z[tr] = az0 + az1;
            ph_n[tr] = an0 + an1;
        }
        __syncthreads();
        if (kh == 0) {
            const float ghr = (ar0 + ar1) + ph_r[tr] + bhr;
            const float ghz = (az0 + az1) + ph_z[tr] + bhz;
            const float ghn = (an0 + an1) + ph_n[tr] + bhn;
            const float r  = sigmf(g_r + ghr);
            const float z  = sigmf(g_z + ghz);
            const float nn = tanhf(g_n + r * ghn);
            const float hnew = (1.0f - z) * nn + z * h_own;
            h_own = hnew;
            ((__half*)h1u[(step + 1) & 1])[tr] = __float2half(hnew);
            if (mode == 0)
                y1[(size_t)(n * NSTEP + s) * 512 + dir * HD + tr] = hnew;
            g_r = gn_r; g_z = gn_z; g_n = gn_n;
        }
        s = s_nxt;
        __syncthreads();
    }
    if (mode == 1 && kh == 0)
        hfin[(size_t)(dir * NSEQ + n) * HD + tr] = h_own;
}

// ---------------- dec_h = w_adj @ [hf,hb] + b_adj ----------------
__global__ __launch_bounds__(256) void adj_kernel(
    const float* __restrict__ hfin, const float* __restrict__ wadjT,
    const float* __restrict__ badj, float* __restrict__ dech)
{
    const int n = blockIdx.x, t = threadIdx.x;
    __shared__ float comb[512];
    comb[t]      = hfin[(size_t)n * HD + t];
    comb[HD + t] = hfin[(size_t)(NSEQ + n) * HD + t];
    __syncthreads();
    float acc = badj[t];
#pragma unroll 8
    for (int f = 0; f < 512; ++f) acc += wadjT[f * HD + t] * comb[f];
    dech[n * HD + t] = acc;
}

// ---------------- decoder: 6 GRU steps + fc1, feeds output back -------------
// Same split-K structure; input matvec (56-wide) split across k-halves.
// inp-n partial must stay separate from recurrent-n (r multiplies only gh_n):
// upper half publishes both via ph_n (recurrent) and ph_in (input).
__global__ __launch_bounds__(512, 2) void decoder_kernel(
    const float* __restrict__ dech, const uint32_t* __restrict__ wTd,
    const float* __restrict__ wihdT, const float* __restrict__ bihd,
    const float* __restrict__ bhhd, const float* __restrict__ wfc1T,
    const float* __restrict__ bfc1, float* __restrict__ out)
{
    const int n = blockIdx.x, t = threadIdx.x;
    const int tr  = t & 255;
    const int kh  = t >> 8;
    const int qb  = kh * 16;
    const int hoff = kh * 64;
    const uint4* wq = (const uint4*)wTd;

    __shared__ __align__(16) uint32_t h1u[2][HD / 2];
    __shared__ float ph_r[HD], ph_z[HD], ph_n[HD], ph_in[HD];
    __shared__ float hfp[HD];
    __shared__ float inp[56];

    L16(LOADW)
    const float bir = bihd[tr], biz = bihd[256 + tr], bin = bihd[512 + tr];
    const float bhr = bhhd[tr], bhz = bhhd[256 + tr], bhn = bhhd[512 + tr];

    float h_own = 0.0f;
    if (kh == 0) {
        const float hv = dech[n * HD + tr];
        h_own = hv;
        ((__half*)h1u[0])[tr] = __float2half(hv);
        hfp[tr] = hv;
    }
    if (t < 56) inp[t] = 0.0f;
    __syncthreads();

    for (int step = 0; step < 6; ++step) {
        const uint32_t* hb = h1u[step & 1];
        float ar0 = 0.f, ar1 = 0.f;
        float az0 = 0.f, az1 = 0.f;
        float an0 = 0.f, an1 = 0.f;
        L16(DOTW)
        float ai_r = 0.f, ai_z = 0.f, ai_n = 0.f;
        const int v0 = kh * 28;
#pragma unroll
        for (int v = 0; v < 28; ++v) {
            const float iv = inp[v0 + v];
            ai_r += wihdT[(v0 + v) * G3 + tr] * iv;
            ai_z += wihdT[(v0 + v) * G3 + 256 + tr] * iv;
            ai_n += wihdT[(v0 + v) * G3 + 512 + tr] * iv;
        }
        if (kh) {
            ph_r[tr]  = (ar0 + ar1) + ai_r;   // r/z: input+recurrent sum OK
            ph_z[tr]  = (az0 + az1) + ai_z;
            ph_n[tr]  = an0 + an1;            // recurrent-n only
            ph_in[tr] = ai_n;                 // input-n only
        }
        __syncthreads();
        if (kh == 0) {
            const float r   = sigmf((ar0 + ar1) + ai_r + ph_r[tr] + bhr + bir);
            const float z   = sigmf((az0 + az1) + ai_z + ph_z[tr] + bhz + biz);
            const float ghn = (an0 + an1) + ph_n[tr] + bhn;
            const float gin = ai_n + ph_in[tr] + bin;
            const float nn  = tanhf(gin + r * ghn);
            const float hnew = (1.0f - z) * nn + z * h_own;
            h_own = hnew;
            ((__half*)h1u[(step + 1) & 1])[tr] = __float2half(hnew);
            hfp[tr] = hnew;
        }
        __syncthreads();
        if (t < 56) {
            float o = bfc1[t];
#pragma unroll 8
            for (int k = 0; k < HD; ++k) o += wfc1T[k * 56 + t] * hfp[k];
            out[n * 336 + step * 56 + t] = o;
            inp[t] = o;
        }
        __syncthreads();
    }
}

// ---------------------------------------------------------------------------
extern "C" void kernel_launch(void* const* d_in, const int* in_sizes, int n_in,
                              void* d_out, int out_size, void* d_ws, size_t ws_size,
                              hipStream_t stream)
{
    const float* x      = (const float*)d_in[0];
    const float* wih1f  = (const float*)d_in[1];
    const float* whh1f  = (const float*)d_in[2];
    const float* bih1f  = (const float*)d_in[3];
    const float* bhh1f  = (const float*)d_in[4];
    const float* wih1b  = (const float*)d_in[5];
    const float* whh1b  = (const float*)d_in[6];
    const float* bih1b  = (const float*)d_in[7];
    const float* bhh1b  = (const float*)d_in[8];
    const float* wih2f  = (const float*)d_in[9];
    const float* whh2f  = (const float*)d_in[10];
    const float* bih2f  = (const float*)d_in[11];
    const float* bhh2f  = (const float*)d_in[12];
    const float* wih2b  = (const float*)d_in[13];
    const float* whh2b  = (const float*)d_in[14];
    const float* bih2b  = (const float*)d_in[15];
    const float* bhh2b  = (const float*)d_in[16];
    const float* wihd   = (const float*)d_in[17];
    const float* whhd   = (const float*)d_in[18];
    const float* bihd   = (const float*)d_in[19];
    const float* bhhd   = (const float*)d_in[20];
    const float* wfc1   = (const float*)d_in[21];
    const float* bfc1   = (const float*)d_in[22];
    const float* wadj   = (const float*)d_in[23];
    const float* badj   = (const float*)d_in[24];

    float* ws = (float*)d_ws;
    float* seqg  = ws + 0;              // 786432
    float* gi1f  = ws + 786432;         // 3145728  (also gi2f, after scan1)
    float* gi1b  = ws + 3932160;        // 3145728  (also gi2b)
    float* y1    = ws + 7077888;        // 2097152
    float* hfin  = ws + 9175040;        // 32768
    float* dech  = ws + 9207808;        // 16384
    uint32_t* wt1f  = (uint32_t*)(ws + 9224192);   // 98304 each
    uint32_t* wt1b  = (uint32_t*)(ws + 9322496);
    uint32_t* wt2f  = (uint32_t*)(ws + 9420800);
    uint32_t* wt2b  = (uint32_t*)(ws + 9519104);
    uint32_t* wtd   = (uint32_t*)(ws + 9617408);
    float* wihdT = ws + 9715712;        // 43008
    float* wadjT = ws + 9758720;        // 131072
    float* wfc1T = ws + 9889792;        // 14336

    pack_whhT<<<dim3(96, 5), 256, 0, stream>>>(
        whh1f, whh1b, whh2f, whh2b, whhd, wt1f, wt1b, wt2f, wt2b, wtd);
    prep_small<<<736, 256, 0, stream>>>(wihd, wadj, wfc1, wihdT, wadjT, wfc1T);
    gather_seq<<<3072, 256, 0, stream>>>(x, seqg);

    // layer 1
    gemm_bias<<<dim3(64, 12, 2), 256, 0, stream>>>(
        seqg, wih1f, wih1b, bih1f, bih1b, gi1f, gi1b, 192);
    gru_scan<<<128, 512, 0, stream>>>(
        gi1f, gi1b, wt1f, wt1b, bhh1f, bhh1b, y1, hfin, 0);

    // layer 2 (gi buffers reused; stream order serializes)
    gemm_bias<<<dim3(64, 12, 2), 256, 0, stream>>>(
        y1, wih2f, wih2b, bih2f, bih2b, gi1f, gi1b, 512);
    gru_scan<<<128, 512, 0, stream>>>(
        gi1f, gi1b, wt2f, wt2b, bhh2f, bhh2b, y1, hfin, 1);

    // decoder head
    adj_kernel<<<64, 256, 0, stream>>>(hfin, wadjT, badj, dech);
    decoder_kernel<<<64, 512, 0, stream>>>(
        dech, wtd, wihdT, bihd, bhhd, wfc1T, bfc1, (float*)d_out);
}